// Round 9
// baseline (185.301 us; speedup 1.0000x reference)
//
#include <hip/hip_runtime.h>

#define Bsz 8
#define Ssz 128
#define Dsz 512
#define D2 1024
#define Lsz 512
#define Rsz 50
#define SLOT 524288        // ushorts per slot (1 MB)
#define BSLOT 65536        // per-b stride in transposed slots (ushorts)
#define OUTMAT 131072

typedef __attribute__((ext_vector_type(8))) _Float16 f16x8;
typedef __attribute__((ext_vector_type(2))) __fp16 fp16x2;
typedef __attribute__((ext_vector_type(4))) float f32x4;

union UV4 { uint4 u; f16x8 h; };
union UH { unsigned short s; _Float16 h; };
union UP { fp16x2 h; unsigned u; };

struct K1Args {
  const float* W1[4];
  const float* b1[4];
};

__device__ __forceinline__ float f16lo(unsigned u) {
  UH x; x.s = (unsigned short)(u & 0xffffu); return (float)x.h;
}
__device__ __forceinline__ float f16hi(unsigned u) {
  UH x; x.s = (unsigned short)(u >> 16); return (float)x.h;
}
__device__ __forceinline__ unsigned pkrtz(float a, float b) {
  UP c; c.h = __builtin_amdgcn_cvt_pkrtz(a, b); return c.u;
}
__device__ __forceinline__ unsigned short f2h(float v) {
  UH x; x.h = (_Float16)v; return x.s;
}
__device__ __forceinline__ float rcpf(float x) {
  return __builtin_amdgcn_rcpf(x);
}

// ---------------------------------------------------------------------------
// Prep (merged): z<4: W1[z] -> W1F f16 fragment order.
// z==4: x -> X16F f16 fragment order. z==5: label W2 -> W2F fragment order.
// ---------------------------------------------------------------------------
__global__ __launch_bounds__(256) void prep_all(
    const float* __restrict__ x, K1Args a, const float* __restrict__ W2,
    unsigned short* __restrict__ W1F, unsigned short* __restrict__ X16F,
    unsigned short* __restrict__ W2F) {
  const int z = blockIdx.z;
  const int t = threadIdx.x;
  if (z < 4) {
    if (blockIdx.x >= 8) return;
    __shared__ float S[64][65];
    const float* __restrict__ W = a.W1[z];
    const int n0 = blockIdx.x * 64;
    const int k0 = blockIdx.y * 64;
    {
      const int kk = t >> 2, c16 = (t & 3) * 16;
      const float* p = W + (k0 + kk) * Lsz + n0 + c16;
#pragma unroll
      for (int c = 0; c < 4; ++c) {
        float4 v = *(const float4*)(p + c * 4);
        S[kk][c16 + c * 4 + 0] = v.x; S[kk][c16 + c * 4 + 1] = v.y;
        S[kk][c16 + c * 4 + 2] = v.z; S[kk][c16 + c * 4 + 3] = v.w;
      }
    }
    __syncthreads();
#pragma unroll
    for (int o = t; o < 512; o += 256) {
      const int lane = o & 63;
      const int ntl = (o >> 6) & 3, kbl = o >> 8;
      const int n_l = ntl * 16 + (lane & 15);
      const int k_l = kbl * 32 + (lane >> 4) * 8;
      uint4 pk;
      pk.x = pkrtz(S[k_l + 0][n_l], S[k_l + 1][n_l]);
      pk.y = pkrtz(S[k_l + 2][n_l], S[k_l + 3][n_l]);
      pk.z = pkrtz(S[k_l + 4][n_l], S[k_l + 5][n_l]);
      pk.w = pkrtz(S[k_l + 6][n_l], S[k_l + 7][n_l]);
      const long addr =
          ((long)((z * 32 + blockIdx.x * 4 + ntl) * 32 + blockIdx.y * 2 + kbl) *
               64 + lane) * 8;
      *(uint4*)(W1F + addr) = pk;
    }
  } else if (z == 4) {
    const int idx = (blockIdx.y * 16 + blockIdx.x) * 256 + t;  // [0,65536)
    const int frag = idx >> 6, lane = idx & 63;
    const int m = (frag >> 4) * 16 + (lane & 15);
    const int k0 = (frag & 15) * 32 + (lane >> 4) * 8;
    const float* p = x + m * Dsz + k0;
    float4 v0 = *(const float4*)p, v1 = *(const float4*)(p + 4);
    uint4 pk = make_uint4(pkrtz(v0.x, v0.y), pkrtz(v0.z, v0.w),
                          pkrtz(v1.x, v1.y), pkrtz(v1.z, v1.w));
    *(uint4*)(X16F + (long)idx * 8) = pk;
  } else {
    if (blockIdx.y != 0 || blockIdx.x >= 16) return;
    const int idx = blockIdx.x * 256 + t;  // [0,4096)
    const int frag = idx >> 6, lane = idx & 63;
    const int o = (frag >> 4) * 16 + (lane & 15);
    const int k0 = (frag & 15) * 32 + (lane >> 4) * 8;
    float v[8];
#pragma unroll
    for (int e = 0; e < 8; ++e)
      v[e] = (o < Rsz) ? W2[(k0 + e) * Rsz + o] : 0.0f;
    uint4 pk = make_uint4(pkrtz(v[0], v[1]), pkrtz(v[2], v[3]),
                          pkrtz(v[4], v[5]), pkrtz(v[6], v[7]));
    *(uint4*)(W2F + (long)idx * 8) = pk;
  }
}

// ---------------------------------------------------------------------------
// Kernel 1: projections, pure f16 MFMA, all K-loop loads coalesced (fragment
// order). Block 64m x 64n, wave 32x32, K=512 (side r = k-half of W1F).
// Epilogue: e = exp(2*(v + b1[left only])) stored f16:
//   scalar-head slots (h<3): transposed [b][n][i]; label slots 6,7: [m][n].
// ---------------------------------------------------------------------------
__global__ __launch_bounds__(256) void gemm_lr_f16f(
    const unsigned short* __restrict__ X16F,
    const unsigned short* __restrict__ W1F, K1Args a,
    unsigned short* __restrict__ U) {
  const int side = blockIdx.z;
  const int h = side >> 1, r = side & 1;
  const float* __restrict__ bias = a.b1[h];
  const int tid = threadIdx.x;
  const int w = tid >> 6, lane = tid & 63;
  const int lm = lane & 15, q = lane >> 4;
  const int mtb = blockIdx.y * 4 + (w & 1) * 2;   // m-tile base (of 16)
  const int ntb = blockIdx.x * 4 + (w >> 1) * 2;  // n-tile base

  f32x4 acc[2][2];
#pragma unroll
  for (int mt = 0; mt < 2; ++mt)
#pragma unroll
    for (int nt = 0; nt < 2; ++nt) {
      acc[mt][nt].x = 0.f; acc[mt][nt].y = 0.f;
      acc[mt][nt].z = 0.f; acc[mt][nt].w = 0.f;
    }

  for (int kb = 0; kb < 16; ++kb) {
    UV4 af[2], bf[2];
#pragma unroll
    for (int mt = 0; mt < 2; ++mt)
      af[mt].u = *(const uint4*)(X16F +
          ((long)((mtb + mt) * 16 + kb) * 64 + lane) * 8);
#pragma unroll
    for (int nt = 0; nt < 2; ++nt)
      bf[nt].u = *(const uint4*)(W1F +
          ((long)((h * 32 + ntb + nt) * 32 + r * 16 + kb) * 64 + lane) * 8);
#pragma unroll
    for (int mt = 0; mt < 2; ++mt)
#pragma unroll
      for (int nt = 0; nt < 2; ++nt)
        acc[mt][nt] = __builtin_amdgcn_mfma_f32_16x16x32_f16(
            af[mt].h, bf[nt].h, acc[mt][nt], 0, 0, 0);
  }

  unsigned short* slot = U + side * SLOT;
  if (h < 3) {
#pragma unroll
    for (int nt = 0; nt < 2; ++nt) {
      const int n_out = (ntb + nt) * 16 + lm;
      const float bb = (r == 0) ? bias[n_out] : 0.0f;
#pragma unroll
      for (int mt = 0; mt < 2; ++mt) {
        const int m0r = (mtb + mt) * 16 + q * 4;
        const float e0 = __expf(2.0f * (acc[mt][nt].x + bb));
        const float e1 = __expf(2.0f * (acc[mt][nt].y + bb));
        const float e2 = __expf(2.0f * (acc[mt][nt].z + bb));
        const float e3 = __expf(2.0f * (acc[mt][nt].w + bb));
        uint2 pr;
        pr.x = pkrtz(e0, e1);
        pr.y = pkrtz(e2, e3);
        const int bi = m0r >> 7, il = m0r & 127;
        *(uint2*)(slot + bi * BSLOT + n_out * Ssz + il) = pr;
      }
    }
  } else {
#pragma unroll
    for (int nt = 0; nt < 2; ++nt) {
      const int n_out = (ntb + nt) * 16 + lm;
      const float bb = (r == 0) ? bias[n_out] : 0.0f;
#pragma unroll
      for (int mt = 0; mt < 2; ++mt) {
#pragma unroll
        for (int reg = 0; reg < 4; ++reg) {
          const int m_out = (mtb + mt) * 16 + q * 4 + reg;
          float v;
          if (reg == 0) v = acc[mt][nt].x;
          else if (reg == 1) v = acc[mt][nt].y;
          else if (reg == 2) v = acc[mt][nt].z;
          else v = acc[mt][nt].w;
          slot[m_out * Lsz + n_out] = f2h(__expf(2.0f * (v + bb)));
        }
      }
    }
  }
}

// ---------------------------------------------------------------------------
// Kernel 2: scalar heads, exp-identity, L-split x2 partials.
// acc = sum_l w2[l] * rcp(ea*eb + 1)  (2 fma + rcp per pair).
// grid (16 tiles, 8 b, 6 = h*2+half); block 256, tile 32x32, 2x2/thread.
// ---------------------------------------------------------------------------
__global__ __launch_bounds__(256) void pair_scalar5(
    const unsigned short* __restrict__ U,
    const float* __restrict__ w2a, const float* __restrict__ w2b,
    const float* __restrict__ w2c, float* __restrict__ P) {
  const int zh = blockIdx.z;
  const int h = zh >> 1, half = zh & 1;
  const int b = blockIdx.y;
  const int it = blockIdx.x >> 2, jt = blockIdx.x & 3;
  if (h == 0 && jt > it) return;   // span: strictly-upper tile unused
  const int i0 = it * 32, j0 = jt * 32;
  const int t = threadIdx.x;
  const int tj = t & 15, ti = t >> 4;

  const unsigned short* __restrict__ A  = U + (2 * h) * SLOT + b * BSLOT;
  const unsigned short* __restrict__ Bt = U + (2 * h + 1) * SLOT + b * BSLOT;
  const float* __restrict__ w2 = (h == 0) ? w2a : (h == 1 ? w2b : w2c);

  __shared__ unsigned short Ls[64][40];
  __shared__ unsigned short Rs[64][40];
  __shared__ float w2s[64];

  float acc00 = 0.f, acc01 = 0.f, acc10 = 0.f, acc11 = 0.f;
  const int sr = t >> 2;        // 0..63
  const int sc = (t & 3) * 8;   // 0,8,16,24
  const int lbase = half * 256;

  for (int lc = 0; lc < 256; lc += 64) {
    __syncthreads();
    const int gl = lbase + lc + sr;
    *(uint4*)&Ls[sr][sc] = *(const uint4*)(A + gl * Ssz + i0 + sc);
    *(uint4*)&Rs[sr][sc] = *(const uint4*)(Bt + gl * Ssz + j0 + sc);
    if (t < 64) w2s[t] = w2[lbase + lc + t];
    __syncthreads();
#pragma unroll 4
    for (int l = 0; l < 64; ++l) {
      const unsigned ua = *(const unsigned*)&Ls[l][ti * 2];
      const unsigned ub = *(const unsigned*)&Rs[l][tj * 2];
      const float ax = f16lo(ua), ay = f16hi(ua);
      const float bx = f16lo(ub), by = f16hi(ub);
      const float wv = w2s[l];
      acc00 = fmaf(wv, rcpf(fmaf(ax, bx, 1.0f)), acc00);
      acc01 = fmaf(wv, rcpf(fmaf(ax, by, 1.0f)), acc01);
      acc10 = fmaf(wv, rcpf(fmaf(ay, bx, 1.0f)), acc10);
      acc11 = fmaf(wv, rcpf(fmaf(ay, by, 1.0f)), acc11);
    }
  }

  float* Pp = P + ((long)(zh * Bsz + b)) * 16384;
  const int i = i0 + ti * 2, j = j0 + tj * 2;
  *(float2*)&Pp[(i + 0) * Ssz + j] = make_float2(acc00, acc01);
  *(float2*)&Pp[(i + 1) * Ssz + j] = make_float2(acc10, acc11);
}

// ---------------------------------------------------------------------------
// Kernel 2.5: combine partials: out = S - 2*(P0+P1) + b2; span symmetrized.
// ---------------------------------------------------------------------------
__global__ __launch_bounds__(128) void combine_scalar(
    const float* __restrict__ P,
    const float* __restrict__ w2a, const float* __restrict__ w2b,
    const float* __restrict__ w2c,
    const float* __restrict__ b2a, const float* __restrict__ b2b,
    const float* __restrict__ b2c,
    float* __restrict__ out) {
  const int h = blockIdx.z;
  const int b = blockIdx.y;
  const int i = blockIdx.x;
  const int t = threadIdx.x;   // j
  const float* __restrict__ w2 = (h == 0) ? w2a : (h == 1 ? w2b : w2c);
  const float bias = (h == 0) ? b2a[0] : (h == 1 ? b2b[0] : b2c[0]);

  __shared__ float red[128];
  float s = w2[t] + w2[t + 128] + w2[t + 256] + w2[t + 384];
  red[t] = s;
  __syncthreads();
  if (t < 64) red[t] += red[t + 64];
  __syncthreads();
  if (t < 32) red[t] += red[t + 32];
  __syncthreads();
  if (t < 16) red[t] += red[t + 16];
  __syncthreads();
  if (t < 8) red[t] += red[t + 8];
  __syncthreads();
  if (t < 4) red[t] += red[t + 4];
  __syncthreads();
  if (t < 2) red[t] += red[t + 2];
  __syncthreads();
  const float S = red[0] + red[1];

  const float* P0 = P + ((long)(h * 2 * Bsz + b)) * 16384;
  const float* P1 = P + ((long)((h * 2 + 1) * Bsz + b)) * 16384;
  int ii = i, jj = t;
  if (h == 0 && t > i) { ii = t; jj = i; }
  const float p = P0[ii * Ssz + jj] + P1[ii * Ssz + jj];
  out[h * OUTMAT + (b * Ssz + i) * Ssz + t] = S - 2.0f * p + bias;
}

// ---------------------------------------------------------------------------
// Kernel 3: label head, f16 MFMA, exp-identity. One i per wg; wave = 16 j
// x 64 o, K=512, R/L prefetched one iter ahead; B-frags L2-hot coalesced.
// Grid (128 i, 2 j-half, 8 b) = 2048 wgs -> 8192 waves (full wave cap).
// ---------------------------------------------------------------------------
__global__ __launch_bounds__(256) void pair_label7(
    const unsigned short* __restrict__ U,
    const unsigned short* __restrict__ W2F,
    const float* __restrict__ b2, float* __restrict__ out) {
  const int b = blockIdx.z;
  const int i = blockIdx.x;
  const int tid = threadIdx.x;
  const int w = tid >> 6, lane = tid & 63;
  const int lm = lane & 15, q = lane >> 4;
  const int jb = blockIdx.y * 64 + w * 16;

  const unsigned short* __restrict__ L0 = U + 6 * SLOT + (b * Ssz + i) * Lsz;
  const unsigned short* __restrict__ Rr = U + 7 * SLOT + (b * Ssz + jb + lm) * Lsz;
  float* out3 = out + 3 * OUTMAT;

  f32x4 acc[4];
#pragma unroll
  for (int nt = 0; nt < 4; ++nt) {
    acc[nt].x = 0.f; acc[nt].y = 0.f;
    acc[nt].z = 0.f; acc[nt].w = 0.f;
  }

  const int kq = q * 8;
  uint4 rc  = *(const uint4*)(Rr + kq);
  uint4 l0c = *(const uint4*)(L0 + kq);

#pragma unroll 1
  for (int kc = 0; kc < Lsz; kc += 32) {
    const int kn = ((kc + 32) & 511) + kq;
    uint4 rn  = *(const uint4*)(Rr + kn);
    uint4 l0n = *(const uint4*)(L0 + kn);
    UV4 bf[4];
    const int kb = kc >> 5;
#pragma unroll
    for (int nt = 0; nt < 4; ++nt)
      bf[nt].u = *(const uint4*)(W2F + ((long)(nt * 16 + kb) * 64 + lane) * 8);

    float rf[8] = {f16lo(rc.x), f16hi(rc.x), f16lo(rc.y), f16hi(rc.y),
                   f16lo(rc.z), f16hi(rc.z), f16lo(rc.w), f16hi(rc.w)};
    float a0[8] = {f16lo(l0c.x), f16hi(l0c.x), f16lo(l0c.y), f16hi(l0c.y),
                   f16lo(l0c.z), f16hi(l0c.z), f16lo(l0c.w), f16hi(l0c.w)};
    float h0[8];
#pragma unroll
    for (int e = 0; e < 8; ++e)
      h0[e] = fmaf(-2.0f, rcpf(fmaf(a0[e], rf[e], 1.0f)), 1.0f);
    UV4 A0;
    A0.u = make_uint4(pkrtz(h0[0], h0[1]), pkrtz(h0[2], h0[3]),
                      pkrtz(h0[4], h0[5]), pkrtz(h0[6], h0[7]));
#pragma unroll
    for (int nt = 0; nt < 4; ++nt)
      acc[nt] = __builtin_amdgcn_mfma_f32_16x16x32_f16(
          A0.h, bf[nt].h, acc[nt], 0, 0, 0);
    rc = rn; l0c = l0n;
  }

#pragma unroll
  for (int nt = 0; nt < 4; ++nt) {
    const int o = nt * 16 + lm;
    if (o >= Rsz) continue;
    const float bias = b2[o];
#pragma unroll
    for (int reg = 0; reg < 4; ++reg) {
      const int j = jb + q * 4 + reg;
      const long base = ((long)((b * Ssz + i) * Ssz) + j) * Rsz;
      float v;
      if (reg == 0) v = acc[nt].x;
      else if (reg == 1) v = acc[nt].y;
      else if (reg == 2) v = acc[nt].z;
      else v = acc[nt].w;
      out3[base + o] = v + bias;
    }
  }
}

extern "C" void kernel_launch(void* const* d_in, const int* in_sizes, int n_in,
                              void* d_out, int out_size, void* d_ws,
                              size_t ws_size, hipStream_t stream) {
  (void)in_sizes; (void)n_in; (void)out_size; (void)ws_size;
  const float* x = (const float*)d_in[0];
  K1Args a;
  a.W1[0] = (const float*)d_in[1];  a.b1[0] = (const float*)d_in[2];
  a.W1[1] = (const float*)d_in[5];  a.b1[1] = (const float*)d_in[6];
  a.W1[2] = (const float*)d_in[9];  a.b1[2] = (const float*)d_in[10];
  a.W1[3] = (const float*)d_in[13]; a.b1[3] = (const float*)d_in[14];
  const float* w2a = (const float*)d_in[3];
  const float* b2a = (const float*)d_in[4];
  const float* w2b = (const float*)d_in[7];
  const float* b2b = (const float*)d_in[8];
  const float* w2c = (const float*)d_in[11];
  const float* b2c = (const float*)d_in[12];
  const float* W2l = (const float*)d_in[15];
  const float* b2l = (const float*)d_in[16];
  float* out = (float*)d_out;

  // ws layout (ushorts): [0, 8*SLOT): 8 f16 ea-slots.
  // [8*SLOT, +2M u16): W1F (4MB, frag order) -- reused as fp32 partials P.
  // then X16F (1MB), then W2F (64KB).
  unsigned short* U    = (unsigned short*)d_ws;
  unsigned short* W1F  = U + 8 * SLOT;
  unsigned short* X16F = U + 8 * SLOT + 4 * (Lsz * D2);
  unsigned short* W2F  = U + 8 * SLOT + 5 * (Lsz * D2);
  float* P = (float*)W1F;

  prep_all<<<dim3(16, 16, 6), 256, 0, stream>>>(x, a, W2l, W1F, X16F, W2F);
  gemm_lr_f16f<<<dim3(8, 16, 8), 256, 0, stream>>>(X16F, W1F, a, U);
  pair_scalar5<<<dim3(16, Bsz, 6), 256, 0, stream>>>(U, w2a, w2b, w2c, P);
  combine_scalar<<<dim3(Ssz, Bsz, 3), 128, 0, stream>>>(
      P, w2a, w2b, w2c, b2a, b2b, b2c, out);
  pair_label7<<<dim3(Ssz, 2, Bsz), 256, 0, stream>>>(U, W2F, b2l, out);
}

// Round 10
// 168.681 us; speedup vs baseline: 1.0985x; 1.0985x over previous
//
#include <hip/hip_runtime.h>

#define Bsz 8
#define Ssz 128
#define Dsz 512
#define D2 1024
#define Lsz 512
#define Rsz 50
#define SLOT 524288        // ushorts per slot (1 MB)
#define BSLOT 65536        // per-b stride in transposed slots (ushorts)
#define OUTMAT 131072

typedef __attribute__((ext_vector_type(8))) _Float16 f16x8;
typedef __attribute__((ext_vector_type(2))) __fp16 fp16x2;
typedef __attribute__((ext_vector_type(4))) float f32x4;

union UV4 { uint4 u; f16x8 h; };
union UH { unsigned short s; _Float16 h; };
union UP { fp16x2 h; unsigned u; };

struct K1Args {
  const float* W1[4];
  const float* b1[4];
};

__device__ __forceinline__ float f16lo(unsigned u) {
  UH x; x.s = (unsigned short)(u & 0xffffu); return (float)x.h;
}
__device__ __forceinline__ float f16hi(unsigned u) {
  UH x; x.s = (unsigned short)(u >> 16); return (float)x.h;
}
__device__ __forceinline__ unsigned pkrtz(float a, float b) {
  UP c; c.h = __builtin_amdgcn_cvt_pkrtz(a, b); return c.u;
}
__device__ __forceinline__ unsigned short f2h(float v) {
  UH x; x.h = (_Float16)v; return x.s;
}
__device__ __forceinline__ float rcpf(float x) {
  return __builtin_amdgcn_rcpf(x);
}

// ---------------------------------------------------------------------------
// Prep (merged): z<4: W1[z] -> W1F f16 fragment order.
// z==4: x -> X16F f16 fragment order. z==5: label W2 -> W2F fragment order.
// ---------------------------------------------------------------------------
__global__ __launch_bounds__(256) void prep_all(
    const float* __restrict__ x, K1Args a, const float* __restrict__ W2,
    unsigned short* __restrict__ W1F, unsigned short* __restrict__ X16F,
    unsigned short* __restrict__ W2F) {
  const int z = blockIdx.z;
  const int t = threadIdx.x;
  if (z < 4) {
    if (blockIdx.x >= 8) return;
    __shared__ float S[64][65];
    const float* __restrict__ W = a.W1[z];
    const int n0 = blockIdx.x * 64;
    const int k0 = blockIdx.y * 64;
    {
      const int kk = t >> 2, c16 = (t & 3) * 16;
      const float* p = W + (k0 + kk) * Lsz + n0 + c16;
#pragma unroll
      for (int c = 0; c < 4; ++c) {
        float4 v = *(const float4*)(p + c * 4);
        S[kk][c16 + c * 4 + 0] = v.x; S[kk][c16 + c * 4 + 1] = v.y;
        S[kk][c16 + c * 4 + 2] = v.z; S[kk][c16 + c * 4 + 3] = v.w;
      }
    }
    __syncthreads();
#pragma unroll
    for (int o = t; o < 512; o += 256) {
      const int lane = o & 63;
      const int ntl = (o >> 6) & 3, kbl = o >> 8;
      const int n_l = ntl * 16 + (lane & 15);
      const int k_l = kbl * 32 + (lane >> 4) * 8;
      uint4 pk;
      pk.x = pkrtz(S[k_l + 0][n_l], S[k_l + 1][n_l]);
      pk.y = pkrtz(S[k_l + 2][n_l], S[k_l + 3][n_l]);
      pk.z = pkrtz(S[k_l + 4][n_l], S[k_l + 5][n_l]);
      pk.w = pkrtz(S[k_l + 6][n_l], S[k_l + 7][n_l]);
      const long addr =
          ((long)((z * 32 + blockIdx.x * 4 + ntl) * 32 + blockIdx.y * 2 + kbl) *
               64 + lane) * 8;
      *(uint4*)(W1F + addr) = pk;
    }
  } else if (z == 4) {
    const int idx = (blockIdx.y * 16 + blockIdx.x) * 256 + t;  // [0,65536)
    const int frag = idx >> 6, lane = idx & 63;
    const int m = (frag >> 4) * 16 + (lane & 15);
    const int k0 = (frag & 15) * 32 + (lane >> 4) * 8;
    const float* p = x + m * Dsz + k0;
    float4 v0 = *(const float4*)p, v1 = *(const float4*)(p + 4);
    uint4 pk = make_uint4(pkrtz(v0.x, v0.y), pkrtz(v0.z, v0.w),
                          pkrtz(v1.x, v1.y), pkrtz(v1.z, v1.w));
    *(uint4*)(X16F + (long)idx * 8) = pk;
  } else {
    if (blockIdx.y != 0 || blockIdx.x >= 16) return;
    const int idx = blockIdx.x * 256 + t;  // [0,4096)
    const int frag = idx >> 6, lane = idx & 63;
    const int o = (frag >> 4) * 16 + (lane & 15);
    const int k0 = (frag & 15) * 32 + (lane >> 4) * 8;
    float v[8];
#pragma unroll
    for (int e = 0; e < 8; ++e)
      v[e] = (o < Rsz) ? W2[(k0 + e) * Rsz + o] : 0.0f;
    uint4 pk = make_uint4(pkrtz(v[0], v[1]), pkrtz(v[2], v[3]),
                          pkrtz(v[4], v[5]), pkrtz(v[6], v[7]));
    *(uint4*)(W2F + (long)idx * 8) = pk;
  }
}

// ---------------------------------------------------------------------------
// Kernel 1: projections, pure f16 MFMA, all K-loop loads coalesced (fragment
// order). Block 64m x 64n, wave 32x32, K=512 (side r = k-half of W1F).
// Epilogue: e = exp(2*(v + b1[left only])) stored f16:
//   scalar-head slots (h<3): transposed [b][n][i]; label slots 6,7: [m][n].
// ---------------------------------------------------------------------------
__global__ __launch_bounds__(256) void gemm_lr_f16f(
    const unsigned short* __restrict__ X16F,
    const unsigned short* __restrict__ W1F, K1Args a,
    unsigned short* __restrict__ U) {
  const int side = blockIdx.z;
  const int h = side >> 1, r = side & 1;
  const float* __restrict__ bias = a.b1[h];
  const int tid = threadIdx.x;
  const int w = tid >> 6, lane = tid & 63;
  const int lm = lane & 15, q = lane >> 4;
  const int mtb = blockIdx.y * 4 + (w & 1) * 2;   // m-tile base (of 16)
  const int ntb = blockIdx.x * 4 + (w >> 1) * 2;  // n-tile base

  f32x4 acc[2][2];
#pragma unroll
  for (int mt = 0; mt < 2; ++mt)
#pragma unroll
    for (int nt = 0; nt < 2; ++nt) {
      acc[mt][nt].x = 0.f; acc[mt][nt].y = 0.f;
      acc[mt][nt].z = 0.f; acc[mt][nt].w = 0.f;
    }

  for (int kb = 0; kb < 16; ++kb) {
    UV4 af[2], bf[2];
#pragma unroll
    for (int mt = 0; mt < 2; ++mt)
      af[mt].u = *(const uint4*)(X16F +
          ((long)((mtb + mt) * 16 + kb) * 64 + lane) * 8);
#pragma unroll
    for (int nt = 0; nt < 2; ++nt)
      bf[nt].u = *(const uint4*)(W1F +
          ((long)((h * 32 + ntb + nt) * 32 + r * 16 + kb) * 64 + lane) * 8);
#pragma unroll
    for (int mt = 0; mt < 2; ++mt)
#pragma unroll
      for (int nt = 0; nt < 2; ++nt)
        acc[mt][nt] = __builtin_amdgcn_mfma_f32_16x16x32_f16(
            af[mt].h, bf[nt].h, acc[mt][nt], 0, 0, 0);
  }

  unsigned short* slot = U + side * SLOT;
  if (h < 3) {
#pragma unroll
    for (int nt = 0; nt < 2; ++nt) {
      const int n_out = (ntb + nt) * 16 + lm;
      const float bb = (r == 0) ? bias[n_out] : 0.0f;
#pragma unroll
      for (int mt = 0; mt < 2; ++mt) {
        const int m0r = (mtb + mt) * 16 + q * 4;
        const float e0 = __expf(2.0f * (acc[mt][nt].x + bb));
        const float e1 = __expf(2.0f * (acc[mt][nt].y + bb));
        const float e2 = __expf(2.0f * (acc[mt][nt].z + bb));
        const float e3 = __expf(2.0f * (acc[mt][nt].w + bb));
        uint2 pr;
        pr.x = pkrtz(e0, e1);
        pr.y = pkrtz(e2, e3);
        const int bi = m0r >> 7, il = m0r & 127;
        *(uint2*)(slot + bi * BSLOT + n_out * Ssz + il) = pr;
      }
    }
  } else {
#pragma unroll
    for (int nt = 0; nt < 2; ++nt) {
      const int n_out = (ntb + nt) * 16 + lm;
      const float bb = (r == 0) ? bias[n_out] : 0.0f;
#pragma unroll
      for (int mt = 0; mt < 2; ++mt) {
#pragma unroll
        for (int reg = 0; reg < 4; ++reg) {
          const int m_out = (mtb + mt) * 16 + q * 4 + reg;
          float v;
          if (reg == 0) v = acc[mt][nt].x;
          else if (reg == 1) v = acc[mt][nt].y;
          else if (reg == 2) v = acc[mt][nt].z;
          else v = acc[mt][nt].w;
          slot[m_out * Lsz + n_out] = f2h(__expf(2.0f * (v + bb)));
        }
      }
    }
  }
}

// ---------------------------------------------------------------------------
// Kernel 2: scalar heads, exp-identity, L-split x2 partials.
// acc = sum_l w2[l] * rcp(ea*eb + 1)  (2 fma + rcp per pair).
// grid (16 tiles, 8 b, 6 = h*2+half); block 256, tile 32x32, 2x2/thread.
// ---------------------------------------------------------------------------
__global__ __launch_bounds__(256) void pair_scalar5(
    const unsigned short* __restrict__ U,
    const float* __restrict__ w2a, const float* __restrict__ w2b,
    const float* __restrict__ w2c, float* __restrict__ P) {
  const int zh = blockIdx.z;
  const int h = zh >> 1, half = zh & 1;
  const int b = blockIdx.y;
  const int it = blockIdx.x >> 2, jt = blockIdx.x & 3;
  if (h == 0 && jt > it) return;   // span: strictly-upper tile unused
  const int i0 = it * 32, j0 = jt * 32;
  const int t = threadIdx.x;
  const int tj = t & 15, ti = t >> 4;

  const unsigned short* __restrict__ A  = U + (2 * h) * SLOT + b * BSLOT;
  const unsigned short* __restrict__ Bt = U + (2 * h + 1) * SLOT + b * BSLOT;
  const float* __restrict__ w2 = (h == 0) ? w2a : (h == 1 ? w2b : w2c);

  __shared__ unsigned short Ls[64][40];
  __shared__ unsigned short Rs[64][40];
  __shared__ float w2s[64];

  float acc00 = 0.f, acc01 = 0.f, acc10 = 0.f, acc11 = 0.f;
  const int sr = t >> 2;        // 0..63
  const int sc = (t & 3) * 8;   // 0,8,16,24
  const int lbase = half * 256;

  for (int lc = 0; lc < 256; lc += 64) {
    __syncthreads();
    const int gl = lbase + lc + sr;
    *(uint4*)&Ls[sr][sc] = *(const uint4*)(A + gl * Ssz + i0 + sc);
    *(uint4*)&Rs[sr][sc] = *(const uint4*)(Bt + gl * Ssz + j0 + sc);
    if (t < 64) w2s[t] = w2[lbase + lc + t];
    __syncthreads();
#pragma unroll 4
    for (int l = 0; l < 64; ++l) {
      const unsigned ua = *(const unsigned*)&Ls[l][ti * 2];
      const unsigned ub = *(const unsigned*)&Rs[l][tj * 2];
      const float ax = f16lo(ua), ay = f16hi(ua);
      const float bx = f16lo(ub), by = f16hi(ub);
      const float wv = w2s[l];
      acc00 = fmaf(wv, rcpf(fmaf(ax, bx, 1.0f)), acc00);
      acc01 = fmaf(wv, rcpf(fmaf(ax, by, 1.0f)), acc01);
      acc10 = fmaf(wv, rcpf(fmaf(ay, bx, 1.0f)), acc10);
      acc11 = fmaf(wv, rcpf(fmaf(ay, by, 1.0f)), acc11);
    }
  }

  float* Pp = P + ((long)(zh * Bsz + b)) * 16384;
  const int i = i0 + ti * 2, j = j0 + tj * 2;
  *(float2*)&Pp[(i + 0) * Ssz + j] = make_float2(acc00, acc01);
  *(float2*)&Pp[(i + 1) * Ssz + j] = make_float2(acc10, acc11);
}

// ---------------------------------------------------------------------------
// Kernel 2.5: combine partials: out = S - 2*(P0+P1) + b2; span symmetrized.
// ---------------------------------------------------------------------------
__global__ __launch_bounds__(128) void combine_scalar(
    const float* __restrict__ P,
    const float* __restrict__ w2a, const float* __restrict__ w2b,
    const float* __restrict__ w2c,
    const float* __restrict__ b2a, const float* __restrict__ b2b,
    const float* __restrict__ b2c,
    float* __restrict__ out) {
  const int h = blockIdx.z;
  const int b = blockIdx.y;
  const int i = blockIdx.x;
  const int t = threadIdx.x;   // j
  const float* __restrict__ w2 = (h == 0) ? w2a : (h == 1 ? w2b : w2c);
  const float bias = (h == 0) ? b2a[0] : (h == 1 ? b2b[0] : b2c[0]);

  __shared__ float red[128];
  float s = w2[t] + w2[t + 128] + w2[t + 256] + w2[t + 384];
  red[t] = s;
  __syncthreads();
  if (t < 64) red[t] += red[t + 64];
  __syncthreads();
  if (t < 32) red[t] += red[t + 32];
  __syncthreads();
  if (t < 16) red[t] += red[t + 16];
  __syncthreads();
  if (t < 8) red[t] += red[t + 8];
  __syncthreads();
  if (t < 4) red[t] += red[t + 4];
  __syncthreads();
  if (t < 2) red[t] += red[t + 2];
  __syncthreads();
  const float S = red[0] + red[1];

  const float* P0 = P + ((long)(h * 2 * Bsz + b)) * 16384;
  const float* P1 = P + ((long)((h * 2 + 1) * Bsz + b)) * 16384;
  int ii = i, jj = t;
  if (h == 0 && t > i) { ii = t; jj = i; }
  const float p = P0[ii * Ssz + jj] + P1[ii * Ssz + jj];
  out[h * OUTMAT + (b * Ssz + i) * Ssz + t] = S - 2.0f * p + bias;
}

// ---------------------------------------------------------------------------
// Kernel 3: label head, canonical LDS-staged double-buffered MFMA.
// One (b,i) per wg; 4 waves, wave w = j-range [w*32, w*32+32), o = 64.
// Per K-chunk (BK=64): R-chunk [128j][64k] (16KB) + B-chunk (8 frags, 8KB,
// SHARED by all 4 waves) staged coalesced into LDS, prefetched one chunk
// ahead into registers. ds_read_b128 fragments; rcp chain; MFMA.
// ---------------------------------------------------------------------------
__global__ __launch_bounds__(256) void pair_label8(
    const unsigned short* __restrict__ U,
    const unsigned short* __restrict__ W2F,
    const float* __restrict__ b2, float* __restrict__ out) {
  const int b = blockIdx.y;
  const int i = blockIdx.x;
  const int tid = threadIdx.x;
  const int w = tid >> 6, lane = tid & 63;
  const int lm = lane & 15, q = lane >> 4;
  const int jb = w * 32;

  const unsigned short* __restrict__ Lrow = U + 6 * SLOT + (b * Ssz + i) * Lsz;
  const unsigned short* __restrict__ Rb0 = U + 7 * SLOT + (long)b * Ssz * Lsz;
  float* out3 = out + 3 * OUTMAT;

  __shared__ unsigned short Rs[2][128][68];   // 34.8 KB
  __shared__ unsigned short Bs[2][8][512];    // 16 KB

  // staging indices (whole wg cooperates)
  const int sr = tid >> 1;                 // R row 0..127
  const int sh = (tid & 1) * 32;           // R k-offset (shorts)
  const unsigned short* Rg = Rb0 + sr * Lsz + sh;
  const int bfrag = tid >> 5;              // B frag 0..7
  const int bo = (tid & 31) * 16;          // shorts within frag
  const int fragN = (bfrag & 3) * 16 + (bfrag >> 2);  // nt*16 + kbl

  f32x4 acc[2][4];
#pragma unroll
  for (int mt = 0; mt < 2; ++mt)
#pragma unroll
    for (int nt = 0; nt < 4; ++nt) {
      acc[mt][nt].x = 0.f; acc[mt][nt].y = 0.f;
      acc[mt][nt].z = 0.f; acc[mt][nt].w = 0.f;
    }

  uint4 rp0, rp1, rp2, rp3, bp0, bp1;
  {
    const unsigned short* p = Rg;
    rp0 = *(const uint4*)(p);      rp1 = *(const uint4*)(p + 8);
    rp2 = *(const uint4*)(p + 16); rp3 = *(const uint4*)(p + 24);
    const unsigned short* bp = W2F + (long)fragN * 512 + bo;
    bp0 = *(const uint4*)(bp);     bp1 = *(const uint4*)(bp + 8);
  }
  *(uint4*)&Rs[0][sr][sh + 0]  = rp0;
  *(uint4*)&Rs[0][sr][sh + 8]  = rp1;
  *(uint4*)&Rs[0][sr][sh + 16] = rp2;
  *(uint4*)&Rs[0][sr][sh + 24] = rp3;
  *(uint4*)&Bs[0][bfrag][bo]     = bp0;
  *(uint4*)&Bs[0][bfrag][bo + 8] = bp1;
  __syncthreads();

#pragma unroll 1
  for (int c = 0; c < 8; ++c) {
    const int buf = c & 1;
    if (c < 7) {
      const unsigned short* p = Rg + (c + 1) * 64;
      rp0 = *(const uint4*)(p);      rp1 = *(const uint4*)(p + 8);
      rp2 = *(const uint4*)(p + 16); rp3 = *(const uint4*)(p + 24);
      const unsigned short* bp = W2F + (long)(fragN + (c + 1) * 2) * 512 + bo;
      bp0 = *(const uint4*)(bp);     bp1 = *(const uint4*)(bp + 8);
    }
    // L values, wave-uniform row (L2-hot broadcast)
    const uint4 lf0 = *(const uint4*)(Lrow + c * 64 + q * 8);
    const uint4 lf1 = *(const uint4*)(Lrow + c * 64 + 32 + q * 8);

#pragma unroll
    for (int kbl = 0; kbl < 2; ++kbl) {
      const uint4 lf = kbl ? lf1 : lf0;
      float ea[8];
      ea[0] = f16lo(lf.x); ea[1] = f16hi(lf.x);
      ea[2] = f16lo(lf.y); ea[3] = f16hi(lf.y);
      ea[4] = f16lo(lf.z); ea[5] = f16hi(lf.z);
      ea[6] = f16lo(lf.w); ea[7] = f16hi(lf.w);
      UV4 bfr[4];
#pragma unroll
      for (int nt = 0; nt < 4; ++nt)
        bfr[nt].u = *(const uint4*)&Bs[buf][kbl * 4 + nt][lane * 8];
#pragma unroll
      for (int mt = 0; mt < 2; ++mt) {
        const uint4 rv =
            *(const uint4*)&Rs[buf][jb + mt * 16 + lm][kbl * 32 + q * 8];
        float eb[8];
        eb[0] = f16lo(rv.x); eb[1] = f16hi(rv.x);
        eb[2] = f16lo(rv.y); eb[3] = f16hi(rv.y);
        eb[4] = f16lo(rv.z); eb[5] = f16hi(rv.z);
        eb[6] = f16lo(rv.w); eb[7] = f16hi(rv.w);
        float hh[8];
#pragma unroll
        for (int e = 0; e < 8; ++e)
          hh[e] = fmaf(-2.0f, rcpf(fmaf(ea[e], eb[e], 1.0f)), 1.0f);
        UV4 A;
        A.u = make_uint4(pkrtz(hh[0], hh[1]), pkrtz(hh[2], hh[3]),
                         pkrtz(hh[4], hh[5]), pkrtz(hh[6], hh[7]));
#pragma unroll
        for (int nt = 0; nt < 4; ++nt)
          acc[mt][nt] = __builtin_amdgcn_mfma_f32_16x16x32_f16(
              A.h, bfr[nt].h, acc[mt][nt], 0, 0, 0);
      }
    }
    if (c < 7) {
      const int nb = buf ^ 1;
      *(uint4*)&Rs[nb][sr][sh + 0]  = rp0;
      *(uint4*)&Rs[nb][sr][sh + 8]  = rp1;
      *(uint4*)&Rs[nb][sr][sh + 16] = rp2;
      *(uint4*)&Rs[nb][sr][sh + 24] = rp3;
      *(uint4*)&Bs[nb][bfrag][bo]     = bp0;
      *(uint4*)&Bs[nb][bfrag][bo + 8] = bp1;
    }
    __syncthreads();
  }

#pragma unroll
  for (int nt = 0; nt < 4; ++nt) {
    const int o = nt * 16 + lm;
    if (o >= Rsz) continue;
    const float bias = b2[o];
#pragma unroll
    for (int mt = 0; mt < 2; ++mt) {
#pragma unroll
      for (int reg = 0; reg < 4; ++reg) {
        const int j = jb + mt * 16 + q * 4 + reg;
        const long base = ((long)((b * Ssz + i) * Ssz) + j) * Rsz;
        float v;
        if (reg == 0) v = acc[mt][nt].x;
        else if (reg == 1) v = acc[mt][nt].y;
        else if (reg == 2) v = acc[mt][nt].z;
        else v = acc[mt][nt].w;
        out3[base + o] = v + bias;
      }
    }
  }
}

extern "C" void kernel_launch(void* const* d_in, const int* in_sizes, int n_in,
                              void* d_out, int out_size, void* d_ws,
                              size_t ws_size, hipStream_t stream) {
  (void)in_sizes; (void)n_in; (void)out_size; (void)ws_size;
  const float* x = (const float*)d_in[0];
  K1Args a;
  a.W1[0] = (const float*)d_in[1];  a.b1[0] = (const float*)d_in[2];
  a.W1[1] = (const float*)d_in[5];  a.b1[1] = (const float*)d_in[6];
  a.W1[2] = (const float*)d_in[9];  a.b1[2] = (const float*)d_in[10];
  a.W1[3] = (const float*)d_in[13]; a.b1[3] = (const float*)d_in[14];
  const float* w2a = (const float*)d_in[3];
  const float* b2a = (const float*)d_in[4];
  const float* w2b = (const float*)d_in[7];
  const float* b2b = (const float*)d_in[8];
  const float* w2c = (const float*)d_in[11];
  const float* b2c = (const float*)d_in[12];
  const float* W2l = (const float*)d_in[15];
  const float* b2l = (const float*)d_in[16];
  float* out = (float*)d_out;

  // ws layout (ushorts): [0, 8*SLOT): 8 f16 ea-slots.
  // [8*SLOT, +2M u16): W1F (4MB, frag order) -- reused as fp32 partials P.
  // then X16F (1MB), then W2F (64KB).
  unsigned short* U    = (unsigned short*)d_ws;
  unsigned short* W1F  = U + 8 * SLOT;
  unsigned short* X16F = U + 8 * SLOT + 4 * (Lsz * D2);
  unsigned short* W2F  = U + 8 * SLOT + 5 * (Lsz * D2);
  float* P = (float*)W1F;

  prep_all<<<dim3(16, 16, 6), 256, 0, stream>>>(x, a, W2l, W1F, X16F, W2F);
  gemm_lr_f16f<<<dim3(8, 16, 8), 256, 0, stream>>>(X16F, W1F, a, U);
  pair_scalar5<<<dim3(16, Bsz, 6), 256, 0, stream>>>(U, w2a, w2b, w2c, P);
  combine_scalar<<<dim3(Ssz, Bsz, 3), 128, 0, stream>>>(
      P, w2a, w2b, w2c, b2a, b2b, b2c, out);
  pair_label8<<<dim3(Ssz, Bsz), 256, 0, stream>>>(U, W2F, b2l, out);
}

// Round 11
// 166.355 us; speedup vs baseline: 1.1139x; 1.0140x over previous
//
#include <hip/hip_runtime.h>

#define Bsz 8
#define Ssz 128
#define Dsz 512
#define D2 1024
#define Lsz 512
#define Rsz 50
#define SLOT 524288        // ushorts per slot (1 MB)
#define BSLOT 65536        // per-b stride in transposed slots (ushorts)
#define OUTMAT 131072

typedef __attribute__((ext_vector_type(8))) _Float16 f16x8;
typedef __attribute__((ext_vector_type(2))) __fp16 fp16x2;
typedef __attribute__((ext_vector_type(4))) float f32x4;

union UV4 { uint4 u; f16x8 h; };
union UH { unsigned short s; _Float16 h; };
union UP { fp16x2 h; unsigned u; };

struct K1Args {
  const float* W1[4];
  const float* b1[4];
};

__device__ __forceinline__ float f16lo(unsigned u) {
  UH x; x.s = (unsigned short)(u & 0xffffu); return (float)x.h;
}
__device__ __forceinline__ float f16hi(unsigned u) {
  UH x; x.s = (unsigned short)(u >> 16); return (float)x.h;
}
__device__ __forceinline__ float f16v(unsigned short s) {
  UH x; x.s = s; return (float)x.h;
}
__device__ __forceinline__ unsigned pkrtz(float a, float b) {
  UP c; c.h = __builtin_amdgcn_cvt_pkrtz(a, b); return c.u;
}
__device__ __forceinline__ unsigned short f2h(float v) {
  UH x; x.h = (_Float16)v; return x.s;
}
__device__ __forceinline__ float rcpf(float x) {
  return __builtin_amdgcn_rcpf(x);
}

// ---------------------------------------------------------------------------
// Prep (merged): z<4: W1[z] -> W1F f16 fragment order.
// z==4: x -> X16F f16 fragment order.
// z==5: x<16: label W2 -> W2F fragment order; x==16..18: Sums[h] = sum(w2_h)
//        + b2_h[0] (for pair_scalar6's S-trick).
// ---------------------------------------------------------------------------
__global__ __launch_bounds__(256) void prep_all(
    const float* __restrict__ x, K1Args a, const float* __restrict__ W2,
    const float* __restrict__ w2a, const float* __restrict__ w2b,
    const float* __restrict__ w2c,
    const float* __restrict__ b2a, const float* __restrict__ b2b,
    const float* __restrict__ b2c,
    unsigned short* __restrict__ W1F, unsigned short* __restrict__ X16F,
    unsigned short* __restrict__ W2F, float* __restrict__ Sums) {
  const int z = blockIdx.z;
  const int t = threadIdx.x;
  if (z < 4) {
    if (blockIdx.x >= 8) return;
    __shared__ float S[64][65];
    const float* __restrict__ W = a.W1[z];
    const int n0 = blockIdx.x * 64;
    const int k0 = blockIdx.y * 64;
    {
      const int kk = t >> 2, c16 = (t & 3) * 16;
      const float* p = W + (k0 + kk) * Lsz + n0 + c16;
#pragma unroll
      for (int c = 0; c < 4; ++c) {
        float4 v = *(const float4*)(p + c * 4);
        S[kk][c16 + c * 4 + 0] = v.x; S[kk][c16 + c * 4 + 1] = v.y;
        S[kk][c16 + c * 4 + 2] = v.z; S[kk][c16 + c * 4 + 3] = v.w;
      }
    }
    __syncthreads();
#pragma unroll
    for (int o = t; o < 512; o += 256) {
      const int lane = o & 63;
      const int ntl = (o >> 6) & 3, kbl = o >> 8;
      const int n_l = ntl * 16 + (lane & 15);
      const int k_l = kbl * 32 + (lane >> 4) * 8;
      uint4 pk;
      pk.x = pkrtz(S[k_l + 0][n_l], S[k_l + 1][n_l]);
      pk.y = pkrtz(S[k_l + 2][n_l], S[k_l + 3][n_l]);
      pk.z = pkrtz(S[k_l + 4][n_l], S[k_l + 5][n_l]);
      pk.w = pkrtz(S[k_l + 6][n_l], S[k_l + 7][n_l]);
      const long addr =
          ((long)((z * 32 + blockIdx.x * 4 + ntl) * 32 + blockIdx.y * 2 + kbl) *
               64 + lane) * 8;
      *(uint4*)(W1F + addr) = pk;
    }
  } else if (z == 4) {
    if (blockIdx.x >= 16) return;
    const int idx = (blockIdx.y * 16 + blockIdx.x) * 256 + t;  // [0,65536)
    const int frag = idx >> 6, lane = idx & 63;
    const int m = (frag >> 4) * 16 + (lane & 15);
    const int k0 = (frag & 15) * 32 + (lane >> 4) * 8;
    const float* p = x + m * Dsz + k0;
    float4 v0 = *(const float4*)p, v1 = *(const float4*)(p + 4);
    uint4 pk = make_uint4(pkrtz(v0.x, v0.y), pkrtz(v0.z, v0.w),
                          pkrtz(v1.x, v1.y), pkrtz(v1.z, v1.w));
    *(uint4*)(X16F + (long)idx * 8) = pk;
  } else {
    if (blockIdx.y != 0) return;
    if (blockIdx.x < 16) {
      const int idx = blockIdx.x * 256 + t;  // [0,4096)
      const int frag = idx >> 6, lane = idx & 63;
      const int o = (frag >> 4) * 16 + (lane & 15);
      const int k0 = (frag & 15) * 32 + (lane >> 4) * 8;
      float v[8];
#pragma unroll
      for (int e = 0; e < 8; ++e)
        v[e] = (o < Rsz) ? W2[(k0 + e) * Rsz + o] : 0.0f;
      uint4 pk = make_uint4(pkrtz(v[0], v[1]), pkrtz(v[2], v[3]),
                            pkrtz(v[4], v[5]), pkrtz(v[6], v[7]));
      *(uint4*)(W2F + (long)idx * 8) = pk;
    } else if (blockIdx.x < 19) {
      const int h = blockIdx.x - 16;
      const float* __restrict__ w2 = (h == 0) ? w2a : (h == 1 ? w2b : w2c);
      const float bb = (h == 0) ? b2a[0] : (h == 1 ? b2b[0] : b2c[0]);
      __shared__ float red[256];
      red[t] = w2[t] + w2[t + 256];
      __syncthreads();
      for (int s = 128; s > 0; s >>= 1) {
        if (t < s) red[t] += red[t + s];
        __syncthreads();
      }
      if (t == 0) Sums[h] = red[0] + bb;
    }
  }
}

// ---------------------------------------------------------------------------
// Kernel 1: projections, pure f16 MFMA, all K-loop loads coalesced (fragment
// order). Block 64m x 64n, wave 32x32, K=512 (side r = k-half of W1F).
// Epilogue: e = exp(2*(v + b1[left only])) stored f16:
//   scalar-head slots (h<3): transposed [b][n][i]; label slots 6,7: [m][n].
// ---------------------------------------------------------------------------
__global__ __launch_bounds__(256) void gemm_lr_f16f(
    const unsigned short* __restrict__ X16F,
    const unsigned short* __restrict__ W1F, K1Args a,
    unsigned short* __restrict__ U) {
  const int side = blockIdx.z;
  const int h = side >> 1, r = side & 1;
  const float* __restrict__ bias = a.b1[h];
  const int tid = threadIdx.x;
  const int w = tid >> 6, lane = tid & 63;
  const int lm = lane & 15, q = lane >> 4;
  const int mtb = blockIdx.y * 4 + (w & 1) * 2;   // m-tile base (of 16)
  const int ntb = blockIdx.x * 4 + (w >> 1) * 2;  // n-tile base

  f32x4 acc[2][2];
#pragma unroll
  for (int mt = 0; mt < 2; ++mt)
#pragma unroll
    for (int nt = 0; nt < 2; ++nt) {
      acc[mt][nt].x = 0.f; acc[mt][nt].y = 0.f;
      acc[mt][nt].z = 0.f; acc[mt][nt].w = 0.f;
    }

  for (int kb = 0; kb < 16; ++kb) {
    UV4 af[2], bf[2];
#pragma unroll
    for (int mt = 0; mt < 2; ++mt)
      af[mt].u = *(const uint4*)(X16F +
          ((long)((mtb + mt) * 16 + kb) * 64 + lane) * 8);
#pragma unroll
    for (int nt = 0; nt < 2; ++nt)
      bf[nt].u = *(const uint4*)(W1F +
          ((long)((h * 32 + ntb + nt) * 32 + r * 16 + kb) * 64 + lane) * 8);
#pragma unroll
    for (int mt = 0; mt < 2; ++mt)
#pragma unroll
      for (int nt = 0; nt < 2; ++nt)
        acc[mt][nt] = __builtin_amdgcn_mfma_f32_16x16x32_f16(
            af[mt].h, bf[nt].h, acc[mt][nt], 0, 0, 0);
  }

  unsigned short* slot = U + side * SLOT;
  if (h < 3) {
#pragma unroll
    for (int nt = 0; nt < 2; ++nt) {
      const int n_out = (ntb + nt) * 16 + lm;
      const float bb = (r == 0) ? bias[n_out] : 0.0f;
#pragma unroll
      for (int mt = 0; mt < 2; ++mt) {
        const int m0r = (mtb + mt) * 16 + q * 4;
        const float e0 = __expf(2.0f * (acc[mt][nt].x + bb));
        const float e1 = __expf(2.0f * (acc[mt][nt].y + bb));
        const float e2 = __expf(2.0f * (acc[mt][nt].z + bb));
        const float e3 = __expf(2.0f * (acc[mt][nt].w + bb));
        uint2 pr;
        pr.x = pkrtz(e0, e1);
        pr.y = pkrtz(e2, e3);
        const int bi = m0r >> 7, il = m0r & 127;
        *(uint2*)(slot + bi * BSLOT + n_out * Ssz + il) = pr;
      }
    }
  } else {
#pragma unroll
    for (int nt = 0; nt < 2; ++nt) {
      const int n_out = (ntb + nt) * 16 + lm;
      const float bb = (r == 0) ? bias[n_out] : 0.0f;
#pragma unroll
      for (int mt = 0; mt < 2; ++mt) {
#pragma unroll
        for (int reg = 0; reg < 4; ++reg) {
          const int m_out = (mtb + mt) * 16 + q * 4 + reg;
          float v;
          if (reg == 0) v = acc[mt][nt].x;
          else if (reg == 1) v = acc[mt][nt].y;
          else if (reg == 2) v = acc[mt][nt].z;
          else v = acc[mt][nt].w;
          slot[m_out * Lsz + n_out] = f2h(__expf(2.0f * (v + bb)));
        }
      }
    }
  }
}

// ---------------------------------------------------------------------------
// Kernel 2: scalar heads, exp-identity, full K, direct write (no combine):
//   out = Sums[h] - 2 * sum_l w2[l] * rcp(ea*eb + 1)
// grid (32 = 8 it x 4 jt, 8 b, 3 h); block 256; tile 16i x 32j; thread =
// (i-pair, j): one a-dword feeds two rcp chains. LDS-staged 64-l chunks.
// Span (h==0): skip tiles fully above diagonal; mirror-write j<=i entries.
// ---------------------------------------------------------------------------
__global__ __launch_bounds__(256) void pair_scalar6(
    const unsigned short* __restrict__ U,
    const float* __restrict__ w2a, const float* __restrict__ w2b,
    const float* __restrict__ w2c, const float* __restrict__ Sums,
    float* __restrict__ out) {
  const int h = blockIdx.z;
  const int b = blockIdx.y;
  const int it = blockIdx.x >> 2, jt = blockIdx.x & 3;
  const int i0 = it * 16, j0 = jt * 32;
  if (h == 0 && i0 + 15 < j0) return;   // span: tile fully above diagonal
  const int t = threadIdx.x;
  const int tj = t & 31;        // j offset
  const int th = t >> 5;        // i-pair index 0..7 -> i = i0 + th*2

  const unsigned short* __restrict__ A  = U + (2 * h) * SLOT + b * BSLOT;
  const unsigned short* __restrict__ Bt = U + (2 * h + 1) * SLOT + b * BSLOT;
  const float* __restrict__ w2 = (h == 0) ? w2a : (h == 1 ? w2b : w2c);

  __shared__ unsigned short As[64][20];   // [l][i], pad keeps 8B align
  __shared__ unsigned short Bs[64][40];   // [l][j], pad keeps 16B align
  __shared__ float w2s[64];

  float acc0 = 0.f, acc1 = 0.f;
  const int sr = t >> 2;         // 0..63 (l row)
  const int scA = (t & 3) * 4;   // 4 u16 per thread
  const int scB = (t & 3) * 8;   // 8 u16 per thread

  for (int lc = 0; lc < Lsz; lc += 64) {
    __syncthreads();
    *(uint2*)&As[sr][scA] = *(const uint2*)(A + (lc + sr) * Ssz + i0 + scA);
    *(uint4*)&Bs[sr][scB] = *(const uint4*)(Bt + (lc + sr) * Ssz + j0 + scB);
    if (t < 64) w2s[t] = w2[lc + t];
    __syncthreads();
#pragma unroll 8
    for (int l = 0; l < 64; ++l) {
      const float wv = w2s[l];
      const unsigned ua = *(const unsigned*)&As[l][th * 2];
      const float a0 = f16lo(ua), a1 = f16hi(ua);
      const float bb = f16v(Bs[l][tj]);
      acc0 = fmaf(wv, rcpf(fmaf(a0, bb, 1.0f)), acc0);
      acc1 = fmaf(wv, rcpf(fmaf(a1, bb, 1.0f)), acc1);
    }
  }

  const float Sh = Sums[h];
  const float v0 = fmaf(-2.0f, acc0, Sh);
  const float v1 = fmaf(-2.0f, acc1, Sh);
  const int i = i0 + th * 2, j = j0 + tj;
  if (h == 0) {
    if (j <= i) {
      out[(b * Ssz + i) * Ssz + j] = v0;
      out[(b * Ssz + j) * Ssz + i] = v0;
    }
    if (j <= i + 1) {
      out[(b * Ssz + i + 1) * Ssz + j] = v1;
      out[(b * Ssz + j) * Ssz + (i + 1)] = v1;
    }
  } else {
    float* o = out + h * OUTMAT;
    o[(b * Ssz + i) * Ssz + j] = v0;
    o[(b * Ssz + i + 1) * Ssz + j] = v1;
  }
}

// ---------------------------------------------------------------------------
// Kernel 3: label head, canonical LDS-staged double-buffered MFMA.
// One (b,i) per wg; 4 waves, wave w = j-range [w*32, w*32+32), o = 64.
// ---------------------------------------------------------------------------
__global__ __launch_bounds__(256) void pair_label8(
    const unsigned short* __restrict__ U,
    const unsigned short* __restrict__ W2F,
    const float* __restrict__ b2, float* __restrict__ out) {
  const int b = blockIdx.y;
  const int i = blockIdx.x;
  const int tid = threadIdx.x;
  const int w = tid >> 6, lane = tid & 63;
  const int lm = lane & 15, q = lane >> 4;
  const int jb = w * 32;

  const unsigned short* __restrict__ Lrow = U + 6 * SLOT + (b * Ssz + i) * Lsz;
  const unsigned short* __restrict__ Rb0 = U + 7 * SLOT + (long)b * Ssz * Lsz;
  float* out3 = out + 3 * OUTMAT;

  __shared__ unsigned short Rs[2][128][68];   // 34.8 KB
  __shared__ unsigned short Bs[2][8][512];    // 16 KB

  const int sr = tid >> 1;                 // R row 0..127
  const int sh = (tid & 1) * 32;           // R k-offset (shorts)
  const unsigned short* Rg = Rb0 + sr * Lsz + sh;
  const int bfrag = tid >> 5;              // B frag 0..7
  const int bo = (tid & 31) * 16;          // shorts within frag
  const int fragN = (bfrag & 3) * 16 + (bfrag >> 2);  // nt*16 + kbl

  f32x4 acc[2][4];
#pragma unroll
  for (int mt = 0; mt < 2; ++mt)
#pragma unroll
    for (int nt = 0; nt < 4; ++nt) {
      acc[mt][nt].x = 0.f; acc[mt][nt].y = 0.f;
      acc[mt][nt].z = 0.f; acc[mt][nt].w = 0.f;
    }

  uint4 rp0, rp1, rp2, rp3, bp0, bp1;
  {
    const unsigned short* p = Rg;
    rp0 = *(const uint4*)(p);      rp1 = *(const uint4*)(p + 8);
    rp2 = *(const uint4*)(p + 16); rp3 = *(const uint4*)(p + 24);
    const unsigned short* bp = W2F + (long)fragN * 512 + bo;
    bp0 = *(const uint4*)(bp);     bp1 = *(const uint4*)(bp + 8);
  }
  *(uint4*)&Rs[0][sr][sh + 0]  = rp0;
  *(uint4*)&Rs[0][sr][sh + 8]  = rp1;
  *(uint4*)&Rs[0][sr][sh + 16] = rp2;
  *(uint4*)&Rs[0][sr][sh + 24] = rp3;
  *(uint4*)&Bs[0][bfrag][bo]     = bp0;
  *(uint4*)&Bs[0][bfrag][bo + 8] = bp1;
  __syncthreads();

#pragma unroll 1
  for (int c = 0; c < 8; ++c) {
    const int buf = c & 1;
    if (c < 7) {
      const unsigned short* p = Rg + (c + 1) * 64;
      rp0 = *(const uint4*)(p);      rp1 = *(const uint4*)(p + 8);
      rp2 = *(const uint4*)(p + 16); rp3 = *(const uint4*)(p + 24);
      const unsigned short* bp = W2F + (long)(fragN + (c + 1) * 2) * 512 + bo;
      bp0 = *(const uint4*)(bp);     bp1 = *(const uint4*)(bp + 8);
    }
    const uint4 lf0 = *(const uint4*)(Lrow + c * 64 + q * 8);
    const uint4 lf1 = *(const uint4*)(Lrow + c * 64 + 32 + q * 8);

#pragma unroll
    for (int kbl = 0; kbl < 2; ++kbl) {
      const uint4 lf = kbl ? lf1 : lf0;
      float ea[8];
      ea[0] = f16lo(lf.x); ea[1] = f16hi(lf.x);
      ea[2] = f16lo(lf.y); ea[3] = f16hi(lf.y);
      ea[4] = f16lo(lf.z); ea[5] = f16hi(lf.z);
      ea[6] = f16lo(lf.w); ea[7] = f16hi(lf.w);
      UV4 bfr[4];
#pragma unroll
      for (int nt = 0; nt < 4; ++nt)
        bfr[nt].u = *(const uint4*)&Bs[buf][kbl * 4 + nt][lane * 8];
#pragma unroll
      for (int mt = 0; mt < 2; ++mt) {
        const uint4 rv =
            *(const uint4*)&Rs[buf][jb + mt * 16 + lm][kbl * 32 + q * 8];
        float eb[8];
        eb[0] = f16lo(rv.x); eb[1] = f16hi(rv.x);
        eb[2] = f16lo(rv.y); eb[3] = f16hi(rv.y);
        eb[4] = f16lo(rv.z); eb[5] = f16hi(rv.z);
        eb[6] = f16lo(rv.w); eb[7] = f16hi(rv.w);
        float hh[8];
#pragma unroll
        for (int e = 0; e < 8; ++e)
          hh[e] = fmaf(-2.0f, rcpf(fmaf(ea[e], eb[e], 1.0f)), 1.0f);
        UV4 A;
        A.u = make_uint4(pkrtz(hh[0], hh[1]), pkrtz(hh[2], hh[3]),
                         pkrtz(hh[4], hh[5]), pkrtz(hh[6], hh[7]));
#pragma unroll
        for (int nt = 0; nt < 4; ++nt)
          acc[mt][nt] = __builtin_amdgcn_mfma_f32_16x16x32_f16(
              A.h, bfr[nt].h, acc[mt][nt], 0, 0, 0);
      }
    }
    if (c < 7) {
      const int nb = buf ^ 1;
      *(uint4*)&Rs[nb][sr][sh + 0]  = rp0;
      *(uint4*)&Rs[nb][sr][sh + 8]  = rp1;
      *(uint4*)&Rs[nb][sr][sh + 16] = rp2;
      *(uint4*)&Rs[nb][sr][sh + 24] = rp3;
      *(uint4*)&Bs[nb][bfrag][bo]     = bp0;
      *(uint4*)&Bs[nb][bfrag][bo + 8] = bp1;
    }
    __syncthreads();
  }

#pragma unroll
  for (int nt = 0; nt < 4; ++nt) {
    const int o = nt * 16 + lm;
    if (o >= Rsz) continue;
    const float bias = b2[o];
#pragma unroll
    for (int mt = 0; mt < 2; ++mt) {
#pragma unroll
      for (int reg = 0; reg < 4; ++reg) {
        const int j = jb + mt * 16 + q * 4 + reg;
        const long base = ((long)((b * Ssz + i) * Ssz) + j) * Rsz;
        float v;
        if (reg == 0) v = acc[mt][nt].x;
        else if (reg == 1) v = acc[mt][nt].y;
        else if (reg == 2) v = acc[mt][nt].z;
        else v = acc[mt][nt].w;
        out3[base + o] = v + bias;
      }
    }
  }
}

extern "C" void kernel_launch(void* const* d_in, const int* in_sizes, int n_in,
                              void* d_out, int out_size, void* d_ws,
                              size_t ws_size, hipStream_t stream) {
  (void)in_sizes; (void)n_in; (void)out_size; (void)ws_size;
  const float* x = (const float*)d_in[0];
  K1Args a;
  a.W1[0] = (const float*)d_in[1];  a.b1[0] = (const float*)d_in[2];
  a.W1[1] = (const float*)d_in[5];  a.b1[1] = (const float*)d_in[6];
  a.W1[2] = (const float*)d_in[9];  a.b1[2] = (const float*)d_in[10];
  a.W1[3] = (const float*)d_in[13]; a.b1[3] = (const float*)d_in[14];
  const float* w2a = (const float*)d_in[3];
  const float* b2a = (const float*)d_in[4];
  const float* w2b = (const float*)d_in[7];
  const float* b2b = (const float*)d_in[8];
  const float* w2c = (const float*)d_in[11];
  const float* b2c = (const float*)d_in[12];
  const float* W2l = (const float*)d_in[15];
  const float* b2l = (const float*)d_in[16];
  float* out = (float*)d_out;

  // ws layout (ushorts): [0, 8*SLOT): 8 f16 ea-slots (scalar heads transposed
  // [b][l][idx]; label 6,7 row-major [m][l]). Then W1F (4MB frag order),
  // X16F (1MB), W2F (64KB), Sums (3 floats).
  unsigned short* U    = (unsigned short*)d_ws;
  unsigned short* W1F  = U + 8 * SLOT;
  unsigned short* X16F = U + 8 * SLOT + 4 * (Lsz * D2);
  unsigned short* W2F  = U + 8 * SLOT + 5 * (Lsz * D2);
  float* Sums = (float*)(W2F + 64 * Lsz);

  prep_all<<<dim3(19, 16, 6), 256, 0, stream>>>(
      x, a, W2l, w2a, w2b, w2c, b2a, b2b, b2c, W1F, X16F, W2F, Sums);
  gemm_lr_f16f<<<dim3(8, 16, 8), 256, 0, stream>>>(X16F, W1F, a, U);
  pair_label8<<<dim3(Ssz, Bsz), 256, 0, stream>>>(U, W2F, b2l, out);
  pair_scalar6<<<dim3(32, Bsz, 3), 256, 0, stream>>>(
      U, w2a, w2b, w2c, Sums, out);
}